// Round 1
// baseline (683.972 us; speedup 1.0000x reference)
//
#include <hip/hip_runtime.h>
#include <math.h>

#define H 1024
#define V 50257
#define S 4096

// d_out layout (floats): [0,V) log_softmax, [V,V+H) h_new, [V+H,V+2H) c_new, [V+2H,V+2H+S) attn_w
#define OUT_H (V)
#define OUT_C (V + H)
#define OUT_A (V + 2 * H)

// ws layout (floats). WS_V padded to 16B alignment for float4 reads.
#define WS_LOGITS 0
#define WS_V      50260            // V rounded up to multiple of 4
#define WS_CTX    (WS_V + H)       // 51284
#define WS_SCORES (WS_CTX + H)     // 52308
#define WS_SB     (WS_SCORES + S)  // 56404
#define WS_PM     (WS_SB + 4)      // 56408 (32 floats)
#define WS_PL     (WS_PM + 32)     // 56440 (32 floats)

// ---------------- K1: LSTM cell. One block per hidden index j; computes 4 gate rows. ----------------
__global__ __launch_bounds__(256) void lstm_kernel(
    const int* __restrict__ word, const float* __restrict__ emb,
    const float* __restrict__ Wih, const float* __restrict__ Whh,
    const float* __restrict__ bih, const float* __restrict__ bhh,
    const float* __restrict__ h0, const float* __restrict__ c0,
    float* __restrict__ out)
{
    int j = blockIdx.x;
    int t = threadIdx.x;
    const float4* x4 = (const float4*)(emb + (size_t)word[0] * H);
    const float4* h4 = (const float4*)h0;
    float acc[4];
#pragma unroll
    for (int r = 0; r < 4; r++) {
        int row = j + r * H;
        const float4* wi = (const float4*)(Wih + (size_t)row * H);
        const float4* wh = (const float4*)(Whh + (size_t)row * H);
        float4 a = wi[t], b = x4[t];
        float s = a.x * b.x + a.y * b.y + a.z * b.z + a.w * b.w;
        float4 c = wh[t], d = h4[t];
        s += c.x * d.x + c.y * d.y + c.z * d.z + c.w * d.w;
        acc[r] = s;
    }
    __shared__ float red[256];
    __shared__ float gates[4];
    for (int r = 0; r < 4; r++) {
        red[t] = acc[r];
        __syncthreads();
        for (int off = 128; off > 0; off >>= 1) {
            if (t < off) red[t] += red[t + off];
            __syncthreads();
        }
        if (t == 0) gates[r] = red[0];
        __syncthreads();
    }
    if (t == 0) {
        float ig = gates[0] + bih[j]         + bhh[j];
        float fg = gates[1] + bih[j + H]     + bhh[j + H];
        float gg = gates[2] + bih[j + 2 * H] + bhh[j + 2 * H];
        float og = gates[3] + bih[j + 3 * H] + bhh[j + 3 * H];
        float si = 1.f / (1.f + expf(-ig));
        float sf = 1.f / (1.f + expf(-fg));
        float so = 1.f / (1.f + expf(-og));
        float cn = sf * c0[j] + si * tanhf(gg);
        float hn = so * tanhf(cn);
        out[OUT_C + j] = cn;
        out[OUT_H + j] = hn;
    }
}

// ---------------- K2: init — sb = attn_b . h_new ; zero v and context (atomic targets) ----------------
__global__ __launch_bounds__(256) void init_kernel(
    const float* __restrict__ attn_b, const float* __restrict__ out, float* __restrict__ ws)
{
    int b = blockIdx.x, t = threadIdx.x;
    if (b == 0) {
        const float* h = out + OUT_H;
        float acc = 0.f;
        for (int k = t; k < H; k += 256) acc += attn_b[k] * h[k];
        __shared__ float red[256];
        red[t] = acc; __syncthreads();
        for (int off = 128; off > 0; off >>= 1) { if (t < off) red[t] += red[t + off]; __syncthreads(); }
        if (t == 0) ws[WS_SB] = red[0];
    } else if (b <= 4) {
        ws[WS_V + (b - 1) * 256 + t] = 0.f;
    } else {
        ws[WS_CTX + (b - 5) * 256 + t] = 0.f;
    }
}

// ---------------- K3: v[k] = sum_j h[j] * attn_W[j,k], split j across blocks with atomics ----------------
__global__ __launch_bounds__(256) void attnv_kernel(
    const float* __restrict__ attn_W, const float* __restrict__ out, float* ws)
{
    int kb = blockIdx.x;  // 0..3  (256 k each)
    int jb = blockIdx.y;  // 0..31 (32 j each)
    int t = threadIdx.x;
    __shared__ float hs[32];
    if (t < 32) hs[t] = out[OUT_H + jb * 32 + t];
    __syncthreads();
    float acc = 0.f;
    const float* base = attn_W + (size_t)(jb * 32) * H + kb * 256 + t;
#pragma unroll 8
    for (int jj = 0; jj < 32; jj++) acc += hs[jj] * base[(size_t)jj * H];
    atomicAdd(&ws[WS_V + kb * 256 + t], acc);
}

// ---------------- K4: scores[s] = enc[s] . v + sb ; wave per s ----------------
__global__ __launch_bounds__(256) void scores_kernel(
    const float* __restrict__ enc, float* ws)
{
    int t = threadIdx.x;
    int wave = t >> 6, lane = t & 63;
    int s = blockIdx.x * 4 + wave;
    const float4* e4 = (const float4*)(enc + (size_t)s * H);
    const float4* v4 = (const float4*)(ws + WS_V);
    float acc = 0.f;
#pragma unroll
    for (int it = 0; it < 4; it++) {
        float4 a = e4[lane + 64 * it];
        float4 b = v4[lane + 64 * it];
        acc += a.x * b.x + a.y * b.y + a.z * b.z + a.w * b.w;
    }
    for (int off = 32; off > 0; off >>= 1) acc += __shfl_xor(acc, off, 64);
    if (lane == 0) ws[WS_SCORES + s] = acc + ws[WS_SB];
}

// ---------------- K5: softmax over S=4096 scores, one block ----------------
__global__ __launch_bounds__(1024) void softmax_kernel(
    const float* __restrict__ ws, float* __restrict__ out)
{
    int t = threadIdx.x;
    float x[4];
    float m = -INFINITY;
#pragma unroll
    for (int i = 0; i < 4; i++) { x[i] = ws[WS_SCORES + t + i * 1024]; m = fmaxf(m, x[i]); }
    __shared__ float red[1024];
    __shared__ float sm, sl;
    red[t] = m; __syncthreads();
    for (int off = 512; off > 0; off >>= 1) { if (t < off) red[t] = fmaxf(red[t], red[t + off]); __syncthreads(); }
    if (t == 0) sm = red[0];
    __syncthreads();
    m = sm;
    float l = 0.f;
#pragma unroll
    for (int i = 0; i < 4; i++) { x[i] = expf(x[i] - m); l += x[i]; }
    red[t] = l; __syncthreads();
    for (int off = 512; off > 0; off >>= 1) { if (t < off) red[t] += red[t + off]; __syncthreads(); }
    if (t == 0) sl = red[0];
    __syncthreads();
    float inv = 1.f / sl;
#pragma unroll
    for (int i = 0; i < 4; i++) out[OUT_A + t + i * 1024] = x[i] * inv;
}

// ---------------- K6: context[k] = sum_s attn_w[s] * enc[s,k], split s across blocks ----------------
__global__ __launch_bounds__(256) void context_kernel(
    const float* __restrict__ enc, const float* __restrict__ out, float* ws)
{
    int kb = blockIdx.x;  // 0..3
    int sb = blockIdx.y;  // 0..63 (64 s each)
    int t = threadIdx.x;
    const float* aw = out + OUT_A;
    float acc = 0.f;
    for (int ss = 0; ss < 64; ss++) {
        int s = sb * 64 + ss;
        acc += aw[s] * enc[(size_t)s * H + kb * 256 + t];
    }
    atomicAdd(&ws[WS_CTX + kb * 256 + t], acc);
}

// ---------------- K7: logits[r] = out_W[r] . feat + out_b[r] ; wave per row (the 412 MB pass) ----------------
__global__ __launch_bounds__(256) void logits_kernel(
    const float* __restrict__ outW, const float* __restrict__ outb,
    const float* __restrict__ out, float* ws)
{
    int t = threadIdx.x;
    __shared__ float feat[2048];
#pragma unroll
    for (int i = 0; i < 8; i++) {
        int idx = t + 256 * i;
        feat[idx] = (idx < H) ? out[OUT_H + idx] : ws[WS_CTX + idx - H];
    }
    __syncthreads();
    int wave = t >> 6, lane = t & 63;
    int r = blockIdx.x * 4 + wave;
    if (r < V) {
        const float4* w4 = (const float4*)(outW + (size_t)r * 2048);
        const float4* f4 = (const float4*)feat;
        float acc = 0.f;
#pragma unroll
        for (int it = 0; it < 8; it++) {
            float4 a = w4[lane + 64 * it];
            float4 b = f4[lane + 64 * it];
            acc += a.x * b.x + a.y * b.y + a.z * b.z + a.w * b.w;
        }
        for (int off = 32; off > 0; off >>= 1) acc += __shfl_xor(acc, off, 64);
        if (lane == 0) ws[WS_LOGITS + r] = acc + outb[r];
    }
}

// ---------------- K8: 32-block online (m, sumexp) partials over logits ----------------
__global__ __launch_bounds__(256) void lse_partial_kernel(float* ws)
{
    int t = threadIdx.x, b = blockIdx.x;
    float m = -INFINITY, l = 0.f;
    for (int i = b * 256 + t; i < V; i += 32 * 256) {
        float x = ws[WS_LOGITS + i];
        float nm = fmaxf(m, x);
        l = l * expf(m - nm) + expf(x - nm);
        m = nm;
    }
    __shared__ float sm[256], sl[256];
    sm[t] = m; sl[t] = l; __syncthreads();
    for (int off = 128; off > 0; off >>= 1) {
        if (t < off) {
            float m2 = sm[t + off], l2 = sl[t + off];
            float nm = fmaxf(sm[t], m2);
            sl[t] = sl[t] * expf(sm[t] - nm) + l2 * expf(m2 - nm);
            sm[t] = nm;
        }
        __syncthreads();
    }
    if (t == 0) { ws[WS_PM + b] = sm[0]; ws[WS_PL + b] = sl[0]; }
}

// ---------------- K9: combine partials, write log_softmax ----------------
__global__ __launch_bounds__(256) void lsout_kernel(const float* __restrict__ ws, float* __restrict__ out)
{
    __shared__ float fm, fl;
    int t = threadIdx.x;
    if (t == 0) {
        float m = -INFINITY, l = 0.f;
        for (int p = 0; p < 32; p++) {
            float m2 = ws[WS_PM + p], l2 = ws[WS_PL + p];
            float nm = fmaxf(m, m2);
            l = l * expf(m - nm) + l2 * expf(m2 - nm);
            m = nm;
        }
        fm = m; fl = logf(l);
    }
    __syncthreads();
    int i = blockIdx.x * 256 + t;
    if (i < V) out[i] = ws[WS_LOGITS + i] - fm - fl;
}

extern "C" void kernel_launch(void* const* d_in, const int* in_sizes, int n_in,
                              void* d_out, int out_size, void* d_ws, size_t ws_size,
                              hipStream_t stream) {
    const int*   word   = (const int*)d_in[0];
    const float* h0     = (const float*)d_in[1];
    const float* c0     = (const float*)d_in[2];
    const float* enc    = (const float*)d_in[3];
    const float* emb    = (const float*)d_in[4];
    const float* Wih    = (const float*)d_in[5];
    const float* Whh    = (const float*)d_in[6];
    const float* bih    = (const float*)d_in[7];
    const float* bhh    = (const float*)d_in[8];
    const float* attn_W = (const float*)d_in[9];
    const float* attn_b = (const float*)d_in[10];
    const float* outW   = (const float*)d_in[11];
    const float* outb   = (const float*)d_in[12];
    float* out = (float*)d_out;
    float* ws  = (float*)d_ws;

    lstm_kernel<<<H, 256, 0, stream>>>(word, emb, Wih, Whh, bih, bhh, h0, c0, out);
    init_kernel<<<9, 256, 0, stream>>>(attn_b, out, ws);
    attnv_kernel<<<dim3(4, 32), 256, 0, stream>>>(attn_W, out, ws);
    scores_kernel<<<S / 4, 256, 0, stream>>>(enc, ws);
    softmax_kernel<<<1, 1024, 0, stream>>>(ws, out);
    context_kernel<<<dim3(4, 64), 256, 0, stream>>>(enc, out, ws);
    logits_kernel<<<(V + 3) / 4, 256, 0, stream>>>(outW, outb, out, ws);
    lse_partial_kernel<<<32, 256, 0, stream>>>(ws);
    lsout_kernel<<<(V + 255) / 256, 256, 0, stream>>>(ws, out);
}